// Round 2
// baseline (425.626 us; speedup 1.0000x reference)
//
#include <hip/hip_runtime.h>
#include <hip/hip_bf16.h>
#include <stdint.h>

#define N_TOT    131072
#define DIM      256
#define KCODES   1024
#define THW      16384        // 16*32*32
#define OUT_ELEMS 33554432ULL // 8*256*16*32*32

typedef short short8 __attribute__((ext_vector_type(8)));
typedef float f32x4  __attribute__((ext_vector_type(4)));

__device__ __forceinline__ unsigned short f2bf_rne(float f) {
  union { float f; unsigned int u; } c; c.f = f;
  unsigned int u = c.u;
  unsigned int r = u + 0x7FFFu + ((u >> 16) & 1u);
  return (unsigned short)(r >> 16);
}

__device__ __forceinline__ void async_cp16(void* lds, const void* gsrc) {
  __builtin_amdgcn_global_load_lds(
      (const __attribute__((address_space(1))) void*)gsrc,
      (__attribute__((address_space(3))) void*)lds, 16, 0, 0);
}

// ---------------- prep: embB in MFMA B-FRAGMENT ORDER (bf16), e2, zero loss ----------
// Fragment order: for codeword k, channel c:
//   cg = k>>4, l15 = k&15, ks = c>>5, q = (c>>3)&3, j = c&7, lane = q*16+l15
//   ushort index = ((cg*8 + ks)*64 + lane)*8 + j
// => a wave's ds_read_b128 at ((cg*8+ks)*64 + lane)*16 B is LINEAR (0 conflicts),
//    and global->LDS staging is a straight linear memcpy.
__global__ __launch_bounds__(64) void k_prep(const float* __restrict__ emb,
                                             unsigned short* __restrict__ embB,
                                             float* __restrict__ e2,
                                             float* __restrict__ lossAcc) {
  const int k = blockIdx.x;
  const int t = threadIdx.x;
  const float4 v = ((const float4*)(emb + (size_t)k * DIM))[t];   // c = 4t..4t+3
  float s = v.x * v.x + v.y * v.y + v.z * v.z + v.w * v.w;
  ushort4 bv;
  bv.x = f2bf_rne(v.x); bv.y = f2bf_rne(v.y);
  bv.z = f2bf_rne(v.z); bv.w = f2bf_rne(v.w);
  const int c0 = 4 * t;
  const int ks = c0 >> 5, q = (c0 >> 3) & 3, j0 = c0 & 7;
  const int lane = q * 16 + (k & 15);
  unsigned short* dst = embB + (size_t)((((k >> 4) * 8 + ks) * 64 + lane) * 8 + j0);
  *(ushort4*)dst = bv;
  #pragma unroll
  for (int m = 32; m; m >>= 1) s += __shfl_xor(s, m, 64);
  if (t == 0) e2[k] = s;
  if (k == 0 && t == 0) *lossAcc = 0.0f;
}

// ---------------- main: fused distance-GEMM + argmin + loss partials ----------------
// 512 blocks x 256 thr (4 waves x 64 rows = 256 rows/block) -> exactly 2 blocks/CU,
// one clean round. Latency hidden by per-wave ILP instead of TLP:
// 4 A-fragments per wave (128 VGPR, register-resident) => per ks step there are
// 4 INDEPENDENT MFMA chains, and each B ds_read_b128 feeds 4 MFMAs (2x reuse vs R0).
// __launch_bounds__(256,2) caps VGPR at 256; need ~215 -> no spill by construction.
// (R1 lesson: forcing 128 VGPR spilled A to scratch -> +400MB HBM traffic.)
// Argmin state packed: 10-bit codeword index in low mantissa bits, v_min_f32 only.
// Validity: codewords span +-1/1024, so near-tie misselection is within the
// codeword-diameter output bound (absmax 0.00195, already measured & passing).
__global__ __launch_bounds__(256, 2) void k_gemm_argmin(
    const float* __restrict__ x, const unsigned short* __restrict__ embB,
    const float* __restrict__ e2, int* __restrict__ idxOut,
    float* __restrict__ lossAcc) {
  __shared__ __align__(16) unsigned short eT[2][16384];   // 2 x 32 KB

  const int tid  = threadIdx.x;
  const int wave = tid >> 6;
  const int lane = tid & 63;
  const int q    = lane >> 4;     // quad 0..3
  const int l15  = lane & 15;
  const int nw0  = blockIdx.x * 256 + wave * 64;   // wave's first row (64 rows/wave)
  const int b    = nw0 >> 14;                      // batch idx (uniform: 16384 % 256 == 0)

  // ---- stage chunk 0 while we build A ----
  {
    const char* gsrc = (const char*)embB;
    char* ldst = (char*)&eT[0][0];
    #pragma unroll
    for (int kk = 0; kk < 8; ++kk)
      async_cp16(ldst + (tid + kk * 256) * 16, gsrc + (size_t)(tid + kk * 256) * 16);
  }

  // ---- A fragments: 64 rows x 256 c, bf16(-2x), register-resident (128 VGPR) ----
  // A-operand layout (verified R1): lane holds A[m = l15][k = q*8 + j], j=0..7.
  short8 A[4][8];
  float x2sum = 0.0f;
  #pragma unroll
  for (int mf = 0; mf < 4; ++mf) {
    const int n   = nw0 + mf * 16 + l15;
    const int thw = n & (THW - 1);
    const float* __restrict__ xr = x + (size_t)b * DIM * THW + thw;
    #pragma unroll
    for (int ks = 0; ks < 8; ++ks) {
      const int c0 = ks * 32 + q * 8;
      short8 a;
      #pragma unroll
      for (int j = 0; j < 8; ++j) {
        float v = xr[(size_t)(c0 + j) * THW];
        x2sum += v * v;
        a[j] = (short)f2bf_rne(-2.0f * v);
      }
      A[mf][ks] = a;
    }
  }

  // packed running min: distance key with codeword index in low 10 bits
  float pmin[4][4];
  #pragma unroll
  for (int mf = 0; mf < 4; ++mf)
    #pragma unroll
    for (int r = 0; r < 4; ++r) pmin[mf][r] = 3.4e38f;

  __syncthreads();   // chunk 0 staged

  // ---- 16 chunks x 64 codewords; prefetch next, consume current, 1 barrier ----
  for (int ch = 0; ch < 16; ++ch) {
    if (ch + 1 < 16) {
      const char* gsrc = (const char*)embB + (size_t)(ch + 1) * 32768;
      char* ldst = (char*)&eT[(ch + 1) & 1][0];
      #pragma unroll
      for (int kk = 0; kk < 8; ++kk)
        async_cp16(ldst + (tid + kk * 256) * 16, gsrc + (size_t)(tid + kk * 256) * 16);
    }
    const unsigned short* __restrict__ buf = &eT[ch & 1][0];
    const int cb = ch * 64;

    // hoist the 4 e2 scalar loads so L2 latency flies over the ds_reads/MFMAs
    float e2c[4];
    #pragma unroll
    for (int g = 0; g < 4; ++g) e2c[g] = e2[cb + g * 16 + l15];

    #pragma unroll
    for (int cgl = 0; cgl < 4; ++cgl) {
      // B-operand: lane holds B[k = q*8+j][n = l15]; fragment-order => linear reads
      short8 B[8];
      #pragma unroll
      for (int ks = 0; ks < 8; ++ks)
        B[ks] = *(const short8*)(buf + (size_t)(((cgl * 8 + ks) * 64 + lane) * 8));

      f32x4 acc[4];
      #pragma unroll
      for (int mf = 0; mf < 4; ++mf) acc[mf] = (f32x4){0.f, 0.f, 0.f, 0.f};
      // ks-major, mf-minor: 4 independent dependent-chains -> ILP covers MFMA latency
      #pragma unroll
      for (int ks = 0; ks < 8; ++ks) {
        #pragma unroll
        for (int mf = 0; mf < 4; ++mf)
          acc[mf] = __builtin_amdgcn_mfma_f32_16x16x32_bf16(A[mf][ks], B[ks], acc[mf], 0, 0, 0);
      }
      // D layout (verified R1): row = q*4 + r, col = l15 (codeword)
      const unsigned int cod = (unsigned int)(cb + cgl * 16 + l15);
      const float e2v = e2c[cgl];
      #pragma unroll
      for (int mf = 0; mf < 4; ++mf) {
        #pragma unroll
        for (int r = 0; r < 4; ++r) {
          float d = acc[mf][r] + e2v;
          unsigned int u = (__float_as_uint(d) & 0xFFFFFC00u) | cod;
          pmin[mf][r] = fminf(pmin[mf][r], __uint_as_float(u));
        }
      }
    }
    __syncthreads();   // prefetch landed (it flew over ~128 MFMAs) + buf-reuse guard
  }

  // ---- reduce argmin across the 16 lanes (cols) holding the same rows ----
  #pragma unroll
  for (int m = 1; m <= 8; m <<= 1)
    #pragma unroll
    for (int mf = 0; mf < 4; ++mf)
      #pragma unroll
      for (int r = 0; r < 4; ++r)
        pmin[mf][r] = fminf(pmin[mf][r], __shfl_xor(pmin[mf][r], m, 64));

  float sstar = 0.0f;
  if (l15 == 0) {
    #pragma unroll
    for (int mf = 0; mf < 4; ++mf)
      #pragma unroll
      for (int r = 0; r < 4; ++r) {
        const unsigned int u = __float_as_uint(pmin[mf][r]);
        idxOut[nw0 + mf * 16 + q * 4 + r] = (int)(u & 1023u);
        sstar += __uint_as_float(u & 0xFFFFFC00u);
      }
  }
  float tot = x2sum + sstar;
  #pragma unroll
  for (int m = 32; m; m >>= 1) tot += __shfl_xor(tot, m, 64);
  if (lane == 0) atomicAdd(lossAcc, tot);
}

// ---------------- epilogue: gather + LDS transpose + float4 coalesced stores --------
// 512 blocks x 256 thr; block = 256 rows x 256 c, c in 4 chunks of 64.
// tile[n][c] stride 65 floats: gather writes (b128) and transpose reads are <=2-way.
// Stores are 16 B/lane, 1 KB/wave-inst, fully coalesced. HBM-write-bound by design.
#define TSTR 65
__global__ __launch_bounds__(256) void k_out(
    const float* __restrict__ emb, const int* __restrict__ idx,
    float* __restrict__ out, const float* __restrict__ lossAcc) {
  __shared__ __align__(16) float tile[256 * TSTR];   // 66560 B
  const int tid  = threadIdx.x;
  const int wave = tid >> 6;
  const int lane = tid & 63;
  const int l15  = lane & 15;
  const int n0   = blockIdx.x * 256;

  if (blockIdx.x == 0 && tid == 0)
    out[OUT_ELEMS] = 1.25f * lossAcc[0] * (1.0f / (float)OUT_ELEMS);

  const int myid = idx[n0 + tid];                  // this thread's row id
  const int b    = n0 >> 14;                       // uniform (16384 % 256 == 0)
  const int thw0 = n0 & (THW - 1);
  float* __restrict__ ob = out + (size_t)b * DIM * THW + thw0;
  const float* __restrict__ er = emb + (size_t)myid * DIM;

  for (int cc = 0; cc < 4; ++cc) {
    const int c0 = cc * 64;
    // gather: thread t fills tile row t with emb[myid][c0..c0+63]
    #pragma unroll
    for (int j = 0; j < 16; ++j) {
      const float4 v = *(const float4*)(er + c0 + 4 * j);
      *(float4*)&tile[tid * TSTR + 4 * j] = v;
    }
    __syncthreads();
    // store: wave w covers n = w*64 .. w*64+63; lane: n = w*64 + 4*l15, c = c0+(l>>4)+4*ci
    #pragma unroll
    for (int ci = 0; ci < 16; ++ci) {
      const int dc = (lane >> 4) + 4 * ci;
      const int nl = wave * 64 + 4 * l15;
      float4 v;
      v.x = tile[(nl + 0) * TSTR + dc];
      v.y = tile[(nl + 1) * TSTR + dc];
      v.z = tile[(nl + 2) * TSTR + dc];
      v.w = tile[(nl + 3) * TSTR + dc];
      *(float4*)(ob + (size_t)(c0 + dc) * THW + nl) = v;
    }
    __syncthreads();   // before next chunk's gather overwrites tile
  }
}

extern "C" void kernel_launch(void* const* d_in, const int* in_sizes, int n_in,
                              void* d_out, int out_size, void* d_ws, size_t ws_size,
                              hipStream_t stream) {
  const float* x   = (const float*)d_in[0];
  const float* emb = (const float*)d_in[1];
  float* out = (float*)d_out;
  char* ws = (char*)d_ws;

  // workspace layout (16B aligned), total ~1.03 MB
  unsigned short* embB = (unsigned short*)(ws);          // 1024*256*2 = 524288 B (frag order)
  float* e2      = (float*)(ws + 524288);                // 4096 B
  int*   idx     = (int*)(ws + 528384);                  // 131072*4 = 524288 B
  float* lossAcc = (float*)(ws + 1052672);               // 4 B

  k_prep<<<KCODES, 64, 0, stream>>>(emb, embB, e2, lossAcc);
  k_gemm_argmin<<<N_TOT / 256, 256, 0, stream>>>(x, embB, e2, idx, lossAcc);
  k_out<<<N_TOT / 256, 256, 0, stream>>>(emb, idx, out, lossAcc);
}

// Round 3
// 343.778 us; speedup vs baseline: 1.2381x; 1.2381x over previous
//
#include <hip/hip_runtime.h>
#include <hip/hip_bf16.h>
#include <stdint.h>

#define N_TOT    131072
#define DIM      256
#define KCODES   1024
#define THW      16384        // 16*32*32
#define OUT_ELEMS 33554432ULL // 8*256*16*32*32

typedef short short8 __attribute__((ext_vector_type(8)));
typedef float f32x4  __attribute__((ext_vector_type(4)));

__device__ __forceinline__ unsigned short f2bf_rne(float f) {
  union { float f; unsigned int u; } c; c.f = f;
  unsigned int u = c.u;
  unsigned int r = u + 0x7FFFu + ((u >> 16) & 1u);
  return (unsigned short)(r >> 16);
}

__device__ __forceinline__ void async_cp16(void* lds, const void* gsrc) {
  __builtin_amdgcn_global_load_lds(
      (const __attribute__((address_space(1))) void*)gsrc,
      (__attribute__((address_space(3))) void*)lds, 16, 0, 0);
}

// ---------------- prep: embB in MFMA B-FRAGMENT ORDER (bf16), e2 ----------
// Fragment order: for codeword k, channel c:
//   cg = k>>4, l15 = k&15, ks = c>>5, q = (c>>3)&3, j = c&7, lane = q*16+l15
//   ushort index = ((cg*8 + ks)*64 + lane)*8 + j
// => a wave's ds_read_b128 at ((cg*8+ks)*64 + lane)*16 B is LINEAR (0 conflicts),
//    and global->LDS staging is a straight linear memcpy.
__global__ __launch_bounds__(64) void k_prep(const float* __restrict__ emb,
                                             unsigned short* __restrict__ embB,
                                             float* __restrict__ e2) {
  const int k = blockIdx.x;
  const int t = threadIdx.x;
  const float4 v = ((const float4*)(emb + (size_t)k * DIM))[t];   // c = 4t..4t+3
  float s = v.x * v.x + v.y * v.y + v.z * v.z + v.w * v.w;
  ushort4 bv;
  bv.x = f2bf_rne(v.x); bv.y = f2bf_rne(v.y);
  bv.z = f2bf_rne(v.z); bv.w = f2bf_rne(v.w);
  const int c0 = 4 * t;
  const int ks = c0 >> 5, q = (c0 >> 3) & 3, j0 = c0 & 7;
  const int lane = q * 16 + (k & 15);
  unsigned short* dst = embB + (size_t)((((k >> 4) * 8 + ks) * 64 + lane) * 8 + j0);
  *(ushort4*)dst = bv;
  #pragma unroll
  for (int m = 32; m; m >>= 1) s += __shfl_xor(s, m, 64);
  if (t == 0) e2[k] = s;
}

// ---------------- main: fused distance-GEMM + argmin + loss partials ----------------
// 512 blocks x 256 thr (4 waves x 64 rows = 256 rows/block), 2 blocks/CU.
// 4 A-fragments per wave (128 VGPR, register-resident): per ks step 4 INDEPENDENT
// MFMA chains; each B ds_read_b128 feeds 4 MFMAs. Plain __launch_bounds__(256):
// R1/R2 lesson — ANY min-waves hint makes the compiler split the unified RF and
// cap arch VGPRs (64/128) -> A spills to scratch (+170..400MB HBM). No hint = no spill.
// LOSS: no global atomics (R0-R2 had 2048-4096 same-address device atomics = a
// serialized ~100+us kernel tail, the unexplained stall). Now: wave shfl-reduce ->
// per-block LDS reduce (aliased onto dead eT) -> ONE plain store per block.
// Argmin state packed: 10-bit codeword index in low mantissa bits, v_min_f32 only.
__global__ __launch_bounds__(256) void k_gemm_argmin(
    const float* __restrict__ x, const unsigned short* __restrict__ embB,
    const float* __restrict__ e2, int* __restrict__ idxOut,
    float* __restrict__ lossPart) {
  __shared__ __align__(16) unsigned short eT[2][16384];   // 2 x 32 KB

  const int tid  = threadIdx.x;
  const int wave = tid >> 6;
  const int lane = tid & 63;
  const int q    = lane >> 4;     // quad 0..3
  const int l15  = lane & 15;
  const int nw0  = blockIdx.x * 256 + wave * 64;   // wave's first row (64 rows/wave)
  const int b    = nw0 >> 14;                      // batch idx (uniform: 16384 % 256 == 0)

  // ---- stage chunk 0 while we build A ----
  {
    const char* gsrc = (const char*)embB;
    char* ldst = (char*)&eT[0][0];
    #pragma unroll
    for (int kk = 0; kk < 8; ++kk)
      async_cp16(ldst + (tid + kk * 256) * 16, gsrc + (size_t)(tid + kk * 256) * 16);
  }

  // ---- A fragments: 64 rows x 256 c, bf16(-2x), register-resident (128 VGPR) ----
  // A-operand layout (verified R1): lane holds A[m = l15][k = q*8 + j], j=0..7.
  short8 A[4][8];
  float x2sum = 0.0f;
  #pragma unroll
  for (int mf = 0; mf < 4; ++mf) {
    const int n   = nw0 + mf * 16 + l15;
    const int thw = n & (THW - 1);
    const float* __restrict__ xr = x + (size_t)b * DIM * THW + thw;
    #pragma unroll
    for (int ks = 0; ks < 8; ++ks) {
      const int c0 = ks * 32 + q * 8;
      short8 a;
      #pragma unroll
      for (int j = 0; j < 8; ++j) {
        float v = xr[(size_t)(c0 + j) * THW];
        x2sum += v * v;
        a[j] = (short)f2bf_rne(-2.0f * v);
      }
      A[mf][ks] = a;
    }
  }

  // packed running min: distance key with codeword index in low 10 bits
  float pmin[4][4];
  #pragma unroll
  for (int mf = 0; mf < 4; ++mf)
    #pragma unroll
    for (int r = 0; r < 4; ++r) pmin[mf][r] = 3.4e38f;

  __syncthreads();   // chunk 0 staged

  // ---- 16 chunks x 64 codewords; prefetch next, consume current, 1 barrier ----
  for (int ch = 0; ch < 16; ++ch) {
    if (ch + 1 < 16) {
      const char* gsrc = (const char*)embB + (size_t)(ch + 1) * 32768;
      char* ldst = (char*)&eT[(ch + 1) & 1][0];
      #pragma unroll
      for (int kk = 0; kk < 8; ++kk)
        async_cp16(ldst + (tid + kk * 256) * 16, gsrc + (size_t)(tid + kk * 256) * 16);
    }
    const unsigned short* __restrict__ buf = &eT[ch & 1][0];
    const int cb = ch * 64;

    // hoist the 4 e2 scalar loads so L2 latency flies over the ds_reads/MFMAs
    float e2c[4];
    #pragma unroll
    for (int g = 0; g < 4; ++g) e2c[g] = e2[cb + g * 16 + l15];

    #pragma unroll
    for (int cgl = 0; cgl < 4; ++cgl) {
      // B-operand: lane holds B[k = q*8+j][n = l15]; fragment-order => linear reads
      short8 B[8];
      #pragma unroll
      for (int ks = 0; ks < 8; ++ks)
        B[ks] = *(const short8*)(buf + (size_t)(((cgl * 8 + ks) * 64 + lane) * 8));

      f32x4 acc[4];
      #pragma unroll
      for (int mf = 0; mf < 4; ++mf) acc[mf] = (f32x4){0.f, 0.f, 0.f, 0.f};
      // ks-major, mf-minor: 4 independent dependent-chains -> ILP covers MFMA latency
      #pragma unroll
      for (int ks = 0; ks < 8; ++ks) {
        #pragma unroll
        for (int mf = 0; mf < 4; ++mf)
          acc[mf] = __builtin_amdgcn_mfma_f32_16x16x32_bf16(A[mf][ks], B[ks], acc[mf], 0, 0, 0);
      }
      // D layout (verified R1): row = q*4 + r, col = l15 (codeword)
      const unsigned int cod = (unsigned int)(cb + cgl * 16 + l15);
      const float e2v = e2c[cgl];
      #pragma unroll
      for (int mf = 0; mf < 4; ++mf) {
        #pragma unroll
        for (int r = 0; r < 4; ++r) {
          float d = acc[mf][r] + e2v;
          unsigned int u = (__float_as_uint(d) & 0xFFFFFC00u) | cod;
          pmin[mf][r] = fminf(pmin[mf][r], __uint_as_float(u));
        }
      }
    }
    __syncthreads();   // prefetch landed (it flew over ~128 MFMAs) + buf-reuse guard
  }

  // ---- reduce argmin across the 16 lanes (cols) holding the same rows ----
  #pragma unroll
  for (int m = 1; m <= 8; m <<= 1)
    #pragma unroll
    for (int mf = 0; mf < 4; ++mf)
      #pragma unroll
      for (int r = 0; r < 4; ++r)
        pmin[mf][r] = fminf(pmin[mf][r], __shfl_xor(pmin[mf][r], m, 64));

  float sstar = 0.0f;
  if (l15 == 0) {
    #pragma unroll
    for (int mf = 0; mf < 4; ++mf)
      #pragma unroll
      for (int r = 0; r < 4; ++r) {
        const unsigned int u = __float_as_uint(pmin[mf][r]);
        idxOut[nw0 + mf * 16 + q * 4 + r] = (int)(u & 1023u);
        sstar += __uint_as_float(u & 0xFFFFFC00u);
      }
  }
  // ---- loss: wave shfl-sum -> per-block LDS sum -> ONE plain store (no atomics) ----
  float tot = x2sum + sstar;
  #pragma unroll
  for (int m = 32; m; m >>= 1) tot += __shfl_xor(tot, m, 64);
  float* red = (float*)&eT[0][0];   // eT dead after final barrier of the chunk loop
  if (lane == 0) red[wave] = tot;
  __syncthreads();
  if (tid == 0) lossPart[blockIdx.x] = red[0] + red[1] + red[2] + red[3];
}

// ---------------- epilogue: gather + LDS transpose + float4 coalesced stores --------
// 512 blocks x 256 thr; block = 256 rows x 256 c, c in 4 chunks of 64.
// tile[n][c] stride 65 floats: gather writes (b128) and transpose reads are <=2-way.
// Stores are 16 B/lane, 1 KB/wave-inst, fully coalesced. HBM-write-bound by design.
// Block 0 / wave 0 additionally sums the 512 gemm loss partials (stream order
// guarantees gemm is done) and writes the loss scalar — no sync, no atomics.
#define TSTR 65
__global__ __launch_bounds__(256) void k_out(
    const float* __restrict__ emb, const int* __restrict__ idx,
    float* __restrict__ out, const float* __restrict__ lossPart) {
  __shared__ __align__(16) float tile[256 * TSTR];   // 66560 B
  const int tid  = threadIdx.x;
  const int wave = tid >> 6;
  const int lane = tid & 63;
  const int l15  = lane & 15;
  const int n0   = blockIdx.x * 256;

  if (blockIdx.x == 0 && tid < 64) {
    float s = 0.0f;
    #pragma unroll
    for (int i = 0; i < 8; ++i) s += lossPart[tid + i * 64];
    #pragma unroll
    for (int m = 32; m; m >>= 1) s += __shfl_xor(s, m, 64);
    if (tid == 0) out[OUT_ELEMS] = 1.25f * s * (1.0f / (float)OUT_ELEMS);
  }

  const int myid = idx[n0 + tid];                  // this thread's row id
  const int b    = n0 >> 14;                       // uniform (16384 % 256 == 0)
  const int thw0 = n0 & (THW - 1);
  float* __restrict__ ob = out + (size_t)b * DIM * THW + thw0;
  const float* __restrict__ er = emb + (size_t)myid * DIM;

  for (int cc = 0; cc < 4; ++cc) {
    const int c0 = cc * 64;
    // gather: thread t fills tile row t with emb[myid][c0..c0+63]
    #pragma unroll
    for (int j = 0; j < 16; ++j) {
      const float4 v = *(const float4*)(er + c0 + 4 * j);
      *(float4*)&tile[tid * TSTR + 4 * j] = v;
    }
    __syncthreads();
    // store: wave w covers n = w*64 .. w*64+63; lane: n = w*64 + 4*l15, c = c0+(l>>4)+4*ci
    #pragma unroll
    for (int ci = 0; ci < 16; ++ci) {
      const int dc = (lane >> 4) + 4 * ci;
      const int nl = wave * 64 + 4 * l15;
      float4 v;
      v.x = tile[(nl + 0) * TSTR + dc];
      v.y = tile[(nl + 1) * TSTR + dc];
      v.z = tile[(nl + 2) * TSTR + dc];
      v.w = tile[(nl + 3) * TSTR + dc];
      *(float4*)(ob + (size_t)(c0 + dc) * THW + nl) = v;
    }
    __syncthreads();   // before next chunk's gather overwrites tile
  }
}

extern "C" void kernel_launch(void* const* d_in, const int* in_sizes, int n_in,
                              void* d_out, int out_size, void* d_ws, size_t ws_size,
                              hipStream_t stream) {
  const float* x   = (const float*)d_in[0];
  const float* emb = (const float*)d_in[1];
  float* out = (float*)d_out;
  char* ws = (char*)d_ws;

  // workspace layout (16B aligned), total ~1.03 MB
  unsigned short* embB = (unsigned short*)(ws);          // 1024*256*2 = 524288 B (frag order)
  float* e2      = (float*)(ws + 524288);                // 4096 B
  int*   idx     = (int*)(ws + 528384);                  // 131072*4 = 524288 B
  float* lossPart = (float*)(ws + 1052672);              // 512*4 = 2048 B

  k_prep<<<KCODES, 64, 0, stream>>>(emb, embB, e2);
  k_gemm_argmin<<<N_TOT / 256, 256, 0, stream>>>(x, embB, e2, idx, lossPart);
  k_out<<<N_TOT / 256, 256, 0, stream>>>(emb, idx, out, lossPart);
}